// Round 3
// baseline (274.958 us; speedup 1.0000x reference)
//
#include <hip/hip_runtime.h>
#include <math.h>

// Chamfer distance, B=8, N=M=8192, D=3, fp32.
// out = mean_m( min_n dist2(x_n, y_m) ) + mean_n( min_m dist2(x_n, y_m) )
//
// dist2 = |x|^2 + (|t|^2 - 2 x.t). Precompute target quads
// (-2t0,-2t1,-2t2,|t|^2); score = fma(x0,T0, fma(x1,T1, fma(x2,T2, T3))).
// R2: register-block Q=8 queries per thread -> 3 fma + 0.5 min per pair,
// scalar quad loads amortized 8x across the lane's queries.

#define B_  8
#define N_  8192
#define M_  8192
#define Q_  8    // queries per thread
#define S_  64   // target-chunk splits (grid.z)

// ws layout (4-byte units):
//   [0,      BN)     : minX (uint bits of per-x min dist2)
//   [BN,  BN+BM)     : minY
//   then quadX float4[BN], quadY float4[BM]

__global__ void prep_kernel(const float* __restrict__ x, const float* __restrict__ y,
                            unsigned* __restrict__ umin,
                            float4* __restrict__ quadX, float4* __restrict__ quadY,
                            int BN, int BM) {
    int i = blockIdx.x * blockDim.x + threadIdx.x;
    if (i >= BN + BM) return;
    umin[i] = 0x7F800000u;  // +inf bits
    const float* src;
    float4* dst;
    int k;
    if (i < BN) { src = x; dst = quadX; k = i; }
    else        { src = y; dst = quadY; k = i - BN; }
    float a0 = src[3 * k + 0];
    float a1 = src[3 * k + 1];
    float a2 = src[3 * k + 2];
    dst[k] = make_float4(-2.0f * a0, -2.0f * a1, -2.0f * a2,
                         fmaf(a0, a0, fmaf(a1, a1, a2 * a2)));
}

// grid: (NQ/(256*Q_), B, S_). Each thread owns Q_ consecutive query points,
// scans CHUNK targets of chunk blockIdx.z, atomicMin-merges per query.
__global__ __launch_bounds__(256)
void minpass_kernel(const float* __restrict__ qpts, const float4* __restrict__ tq,
                    unsigned* __restrict__ omin, int NQ, int NT) {
    const int b   = blockIdx.y;
    const int it  = blockIdx.x * blockDim.x + threadIdx.x;  // thread index in query dim
    const int iq0 = it * Q_;                                // first query of this thread
    const int CHUNK = NT / S_;

    // Load Q_ query points (24 contiguous floats -> merged vector loads).
    const float* qp = qpts + ((long)b * NQ + iq0) * 3;
    float qx[Q_], qy[Q_], qz[Q_];
#pragma unroll
    for (int i = 0; i < Q_; ++i) {
        qx[i] = qp[3 * i + 0];
        qy[i] = qp[3 * i + 1];
        qz[i] = qp[3 * i + 2];
    }

    // Wave-uniform target base -> scalar (s_load) quad streaming.
    const float4* base = tq + (long)b * NT + (long)blockIdx.z * CHUNK;

    float m[Q_];
#pragma unroll
    for (int i = 0; i < Q_; ++i) m[i] = __builtin_inff();

    for (int j = 0; j < CHUNK; j += 2) {
        const float4 ta = base[j + 0];
        const float4 tb = base[j + 1];
#pragma unroll
        for (int i = 0; i < Q_; ++i) {
            float sa = fmaf(qx[i], ta.x, fmaf(qy[i], ta.y, fmaf(qz[i], ta.z, ta.w)));
            float sb = fmaf(qx[i], tb.x, fmaf(qy[i], tb.y, fmaf(qz[i], tb.z, tb.w)));
            m[i] = fminf(m[i], fminf(sa, sb));   // -> v_min3_f32
        }
    }

    unsigned* op = omin + (long)b * NQ + iq0;
#pragma unroll
    for (int i = 0; i < Q_; ++i) {
        float xn = fmaf(qx[i], qx[i], fmaf(qy[i], qy[i], qz[i] * qz[i]));
        float d  = fmaxf(m[i] + xn, 0.0f);       // clamp cancellation; dist2 >= 0
        atomicMin(op + i, __float_as_uint(d));   // uint-ordered == float-ordered for >=0
    }
}

// Single-block deterministic reduction: out = (sum of all mins) / 65536.
__global__ __launch_bounds__(1024)
void reduce_kernel(const unsigned* __restrict__ umin, float* __restrict__ out,
                   int total, float scale) {
    float s = 0.0f;
    for (int i = threadIdx.x; i < total; i += blockDim.x)
        s += __uint_as_float(umin[i]);
    for (int off = 32; off > 0; off >>= 1)
        s += __shfl_down(s, off, 64);
    __shared__ float wsum[16];
    const int lane = threadIdx.x & 63;
    const int w    = threadIdx.x >> 6;
    if (lane == 0) wsum[w] = s;
    __syncthreads();
    if (threadIdx.x == 0) {
        float t = 0.0f;
        const int nw = blockDim.x >> 6;
        for (int i = 0; i < nw; ++i) t += wsum[i];
        out[0] = t * scale;
    }
}

extern "C" void kernel_launch(void* const* d_in, const int* in_sizes, int n_in,
                              void* d_out, int out_size, void* d_ws, size_t ws_size,
                              hipStream_t stream) {
    const float* x = (const float*)d_in[0];  // [8, 8192, 3]
    const float* y = (const float*)d_in[1];  // [8, 8192, 3]
    float* out = (float*)d_out;

    const int BN = B_ * N_;
    const int BM = B_ * M_;

    unsigned* umin  = (unsigned*)d_ws;
    float4*   quadX = (float4*)((char*)d_ws + (size_t)(BN + BM) * 4);
    float4*   quadY = quadX + BN;

    prep_kernel<<<(BN + BM + 255) / 256, 256, 0, stream>>>(x, y, umin, quadX, quadY, BN, BM);

    // per-x mins: queries = x, targets = y quads. grid: (8192/(256*8), 8, 64)
    minpass_kernel<<<dim3(N_ / (256 * Q_), B_, S_), 256, 0, stream>>>(x, quadY, umin, N_, M_);
    // per-y mins: queries = y, targets = x quads
    minpass_kernel<<<dim3(M_ / (256 * Q_), B_, S_), 256, 0, stream>>>(y, quadX, umin + BN, M_, N_);

    reduce_kernel<<<1, 1024, 0, stream>>>(umin, out, BN + BM, 1.0f / 65536.0f);
}

// Round 4
// 204.478 us; speedup vs baseline: 1.3447x; 1.3447x over previous
//
#include <hip/hip_runtime.h>
#include <math.h>

// Chamfer distance, B=8, N=M=8192, D=3, fp32.
// out = mean_m( min_n dist2 ) + mean_n( min_m dist2 )
//
// dist2 = |x|^2 + (|t|^2 - 2 x.t); target quads (-2t0,-2t1,-2t2,|t|^2)
// stream through the scalar pipe (wave-uniform index -> s_load).
// R3: NO atomics. Each (query, target-split) writes a partial min with a
// plain coalesced float4 store; merge kernel min-reduces over splits and
// block-sums; 1-wave final kernel emits the scalar. (R2 post-mortem:
// 4.19M atomicMin = 128 MiB of 32B-granule RMW = 1.43 TB/s write-bound.)

#define B_  8
#define N_  8192
#define M_  8192
#define Q_  4    // queries per thread
#define S_  16   // target-chunk splits (grid.z)

// ws layout:
//   quadX float4[BN], quadY float4[BM]              (2 MB)
//   partX float[S_][BN]                             (4 MB)
//   partY float[S_][BM]                             (4 MB)
//   bsum  float[512]

__global__ void prep_kernel(const float* __restrict__ x, const float* __restrict__ y,
                            float4* __restrict__ quadX, float4* __restrict__ quadY,
                            int BN, int BM) {
    int i = blockIdx.x * blockDim.x + threadIdx.x;
    if (i >= BN + BM) return;
    const float* src;
    float4* dst;
    int k;
    if (i < BN) { src = x; dst = quadX; k = i; }
    else        { src = y; dst = quadY; k = i - BN; }
    float a0 = src[3 * k + 0];
    float a1 = src[3 * k + 1];
    float a2 = src[3 * k + 2];
    dst[k] = make_float4(-2.0f * a0, -2.0f * a1, -2.0f * a2,
                         fmaf(a0, a0, fmaf(a1, a1, a2 * a2)));
}

// grid: (NQ/(256*Q_), B, S_). Thread owns Q_=4 consecutive queries, scans its
// target chunk, stores one float4 of partial mins (coalesced, no atomics).
__global__ __launch_bounds__(256)
void minpass_kernel(const float* __restrict__ qpts, const float4* __restrict__ tq,
                    float* __restrict__ part, int NQ, int NT) {
    const int b   = blockIdx.y;
    const int s   = blockIdx.z;
    const int it  = blockIdx.x * blockDim.x + threadIdx.x;
    const int iq0 = it * Q_;
    const int CHUNK = NT / S_;

    // 4 query points = 48 contiguous bytes -> 3 coalesced float4 loads.
    const float4* qp4 = (const float4*)(qpts + ((long)b * NQ + iq0) * 3);
    const float4 f0 = qp4[0];  // x0 y0 z0 x1
    const float4 f1 = qp4[1];  // y1 z1 x2 y2
    const float4 f2 = qp4[2];  // z2 x3 y3 z3
    const float qx[Q_] = {f0.x, f0.w, f1.z, f2.y};
    const float qy[Q_] = {f0.y, f1.x, f1.w, f2.z};
    const float qz[Q_] = {f0.z, f1.y, f2.x, f2.w};

    // Wave-uniform target base -> scalar quad streaming.
    const float4* base = tq + (long)b * NT + (long)s * CHUNK;

    float m[Q_];
#pragma unroll
    for (int i = 0; i < Q_; ++i) m[i] = __builtin_inff();

    for (int j = 0; j < CHUNK; j += 4) {
        const float4 ta = base[j + 0];
        const float4 tb = base[j + 1];
        const float4 tc = base[j + 2];
        const float4 td = base[j + 3];
#pragma unroll
        for (int i = 0; i < Q_; ++i) {
            float sa = fmaf(qx[i], ta.x, fmaf(qy[i], ta.y, fmaf(qz[i], ta.z, ta.w)));
            float sb = fmaf(qx[i], tb.x, fmaf(qy[i], tb.y, fmaf(qz[i], tb.z, tb.w)));
            float sc = fmaf(qx[i], tc.x, fmaf(qy[i], tc.y, fmaf(qz[i], tc.z, tc.w)));
            float sd = fmaf(qx[i], td.x, fmaf(qy[i], td.y, fmaf(qz[i], td.z, td.w)));
            float t  = fminf(fminf(sa, sb), sc);      // -> v_min3
            m[i] = fminf(fminf(t, sd), m[i]);         // -> v_min3
        }
    }

    float4 d;
    {
        float xn0 = fmaf(qx[0], qx[0], fmaf(qy[0], qy[0], qz[0] * qz[0]));
        float xn1 = fmaf(qx[1], qx[1], fmaf(qy[1], qy[1], qz[1] * qz[1]));
        float xn2 = fmaf(qx[2], qx[2], fmaf(qy[2], qy[2], qz[2] * qz[2]));
        float xn3 = fmaf(qx[3], qx[3], fmaf(qy[3], qy[3], qz[3] * qz[3]));
        d.x = fmaxf(m[0] + xn0, 0.0f);
        d.y = fmaxf(m[1] + xn1, 0.0f);
        d.z = fmaxf(m[2] + xn2, 0.0f);
        d.w = fmaxf(m[3] + xn3, 0.0f);
    }
    // part[s][b*NQ + iq0 .. +3] — consecutive threads write consecutive 16B.
    *(float4*)(part + (long)s * (B_ * (long)NQ) + (long)b * NQ + iq0) = d;
}

// One thread per query slot: min over S_ partials, then block sum.
// grid.x = (BN+BM)/256; blocks [0,256) read partX, [256,512) read partY.
__global__ __launch_bounds__(256)
void merge_kernel(const float* __restrict__ partX, const float* __restrict__ partY,
                  float* __restrict__ bsum, int BN) {
    const int g = blockIdx.x * blockDim.x + threadIdx.x;
    const float* base = (g < BN) ? (partX + g) : (partY + (g - BN));

    float m = __builtin_inff();
#pragma unroll
    for (int s = 0; s < S_; ++s)
        m = fminf(m, base[(long)s * BN]);   // stride BN floats; coalesced per s

    // block reduction (deterministic)
    for (int off = 32; off > 0; off >>= 1)
        m += __shfl_down(m, off, 64);
    __shared__ float wsum[4];
    const int lane = threadIdx.x & 63;
    const int w    = threadIdx.x >> 6;
    if (lane == 0) wsum[w] = m;
    __syncthreads();
    if (threadIdx.x == 0)
        bsum[blockIdx.x] = (wsum[0] + wsum[1]) + (wsum[2] + wsum[3]);
}

// Single wave: deterministic sum of 512 block partials, scaled.
__global__ __launch_bounds__(64)
void final_kernel(const float* __restrict__ bsum, float* __restrict__ out,
                  int nb, float scale) {
    float s = 0.0f;
    for (int k = threadIdx.x; k < nb; k += 64)
        s += bsum[k];
    for (int off = 32; off > 0; off >>= 1)
        s += __shfl_down(s, off, 64);
    if (threadIdx.x == 0) out[0] = s * scale;
}

extern "C" void kernel_launch(void* const* d_in, const int* in_sizes, int n_in,
                              void* d_out, int out_size, void* d_ws, size_t ws_size,
                              hipStream_t stream) {
    const float* x = (const float*)d_in[0];  // [8, 8192, 3]
    const float* y = (const float*)d_in[1];  // [8, 8192, 3]
    float* out = (float*)d_out;

    const int BN = B_ * N_;
    const int BM = B_ * M_;

    float4* quadX = (float4*)d_ws;
    float4* quadY = quadX + BN;
    float*  partX = (float*)(quadY + BM);
    float*  partY = partX + (size_t)S_ * BN;
    float*  bsum  = partY + (size_t)S_ * BM;

    prep_kernel<<<(BN + BM + 255) / 256, 256, 0, stream>>>(x, y, quadX, quadY, BN, BM);

    // per-x mins: queries = x, targets = y quads. grid (8, 8, 16)
    minpass_kernel<<<dim3(N_ / (256 * Q_), B_, S_), 256, 0, stream>>>(x, quadY, partX, N_, M_);
    // per-y mins: queries = y, targets = x quads
    minpass_kernel<<<dim3(M_ / (256 * Q_), B_, S_), 256, 0, stream>>>(y, quadX, partY, M_, N_);

    const int nb = (BN + BM) / 256;  // 512
    merge_kernel<<<nb, 256, 0, stream>>>(partX, partY, bsum, BN);
    final_kernel<<<1, 64, 0, stream>>>(bsum, out, nb, 1.0f / 65536.0f);
}

// Round 5
// 139.885 us; speedup vs baseline: 1.9656x; 1.4618x over previous
//
#include <hip/hip_runtime.h>
#include <math.h>

// Chamfer distance, B=8, N=M=8192, D=3, fp32.
// out = mean_m( min_n dist2 ) + mean_n( min_m dist2 )
//
// dist2 = |q|^2 + (|t|^2 - 2 q.t). R4: single fused minpass dispatch:
//  - grid.z 0..31: z<16 -> queries=x targets=y; z>=16 -> queries=y targets=x
//  - each block computes its 512 target quads (-2t, |t|^2) from raw points
//    into 8KB LDS (kills prep kernel + quad round-trip + s_load latency);
//    inner loop reads quads via uniform-address ds_read_b128 (broadcast).
//  - Q=4 queries/thread in VGPRs; 3 fma + 0.5 min3 per pair.
//  - no atomics: per-(query,split) partial mins stored as coalesced float4
//    (R2 lesson: device atomicMin = 32B-granule RMW = write-bound).
// 2048 blocks = 8/CU = 32 waves/CU.

#define B_      8
#define N_      8192
#define Q_      4            // queries per thread
#define S_      16           // target splits per pass
#define CHUNK_  (N_ / S_)    // 512 targets per block

// ws layout: partX float[S_][B_*N_] (4MB), partY float[S_][B_*N_] (4MB), bsum[512]

__global__ __launch_bounds__(256)
void minpass_kernel(const float* __restrict__ x, const float* __restrict__ y,
                    float* __restrict__ partX, float* __restrict__ partY) {
    __shared__ float4 sq[CHUNK_];

    const int b    = blockIdx.y;
    const int z    = blockIdx.z;       // 0..31
    const int pass = z >> 4;           // 0: q=x,t=y   1: q=y,t=x
    const int s    = z & (S_ - 1);

    const float* qpts = pass ? y : x;
    const float* tpts = pass ? x : y;
    float*       part = pass ? partY : partX;

    // ---- stage: compute 512 target quads into LDS (2 per thread) ----
    {
        const float* tb = tpts + ((long)b * N_ + s * CHUNK_) * 3;
        const float* p  = tb + 6 * threadIdx.x;
        float a0 = p[0], a1 = p[1], a2 = p[2];
        float a3 = p[3], a4 = p[4], a5 = p[5];
        sq[2 * threadIdx.x + 0] = make_float4(-2.0f * a0, -2.0f * a1, -2.0f * a2,
                                              fmaf(a0, a0, fmaf(a1, a1, a2 * a2)));
        sq[2 * threadIdx.x + 1] = make_float4(-2.0f * a3, -2.0f * a4, -2.0f * a5,
                                              fmaf(a3, a3, fmaf(a4, a4, a5 * a5)));
    }
    __syncthreads();

    // ---- queries: 4 consecutive points = 48B -> 3 coalesced float4 loads ----
    const int iq0 = (blockIdx.x * blockDim.x + threadIdx.x) * Q_;
    const float4* qp4 = (const float4*)(qpts + ((long)b * N_ + iq0) * 3);
    const float4 f0 = qp4[0];  // x0 y0 z0 x1
    const float4 f1 = qp4[1];  // y1 z1 x2 y2
    const float4 f2 = qp4[2];  // z2 x3 y3 z3
    const float qx[Q_] = {f0.x, f0.w, f1.z, f2.y};
    const float qy[Q_] = {f0.y, f1.x, f1.w, f2.z};
    const float qz[Q_] = {f0.z, f1.y, f2.x, f2.w};

    float m[Q_];
#pragma unroll
    for (int i = 0; i < Q_; ++i) m[i] = __builtin_inff();

    // ---- scan: uniform-address LDS broadcast reads ----
    for (int j = 0; j < CHUNK_; j += 4) {
        const float4 ta = sq[j + 0];
        const float4 tb = sq[j + 1];
        const float4 tc = sq[j + 2];
        const float4 td = sq[j + 3];
#pragma unroll
        for (int i = 0; i < Q_; ++i) {
            float sa = fmaf(qx[i], ta.x, fmaf(qy[i], ta.y, fmaf(qz[i], ta.z, ta.w)));
            float sb = fmaf(qx[i], tb.x, fmaf(qy[i], tb.y, fmaf(qz[i], tb.z, tb.w)));
            float sc = fmaf(qx[i], tc.x, fmaf(qy[i], tc.y, fmaf(qz[i], tc.z, tc.w)));
            float sd = fmaf(qx[i], td.x, fmaf(qy[i], td.y, fmaf(qz[i], td.z, td.w)));
            float t  = fminf(fminf(sa, sb), sc);   // -> v_min3
            m[i]     = fminf(fminf(t, sd), m[i]);  // -> v_min3
        }
    }

    // ---- emit partial mins (plain coalesced store) ----
    float4 d;
    {
        float xn0 = fmaf(qx[0], qx[0], fmaf(qy[0], qy[0], qz[0] * qz[0]));
        float xn1 = fmaf(qx[1], qx[1], fmaf(qy[1], qy[1], qz[1] * qz[1]));
        float xn2 = fmaf(qx[2], qx[2], fmaf(qy[2], qy[2], qz[2] * qz[2]));
        float xn3 = fmaf(qx[3], qx[3], fmaf(qy[3], qy[3], qz[3] * qz[3]));
        d.x = fmaxf(m[0] + xn0, 0.0f);   // clamp cancellation; dist2 >= 0
        d.y = fmaxf(m[1] + xn1, 0.0f);
        d.z = fmaxf(m[2] + xn2, 0.0f);
        d.w = fmaxf(m[3] + xn3, 0.0f);
    }
    *(float4*)(part + (long)s * (B_ * N_) + (long)b * N_ + iq0) = d;
}

// One thread per query slot: min over S_ partials, then deterministic block sum.
__global__ __launch_bounds__(256)
void merge_kernel(const float* __restrict__ partX, const float* __restrict__ partY,
                  float* __restrict__ bsum, int BN) {
    const int g = blockIdx.x * blockDim.x + threadIdx.x;
    const float* base = (g < BN) ? (partX + g) : (partY + (g - BN));

    float m = __builtin_inff();
#pragma unroll
    for (int s = 0; s < S_; ++s)
        m = fminf(m, base[(long)s * BN]);

    for (int off = 32; off > 0; off >>= 1)
        m += __shfl_down(m, off, 64);
    __shared__ float wsum[4];
    const int lane = threadIdx.x & 63;
    const int w    = threadIdx.x >> 6;
    if (lane == 0) wsum[w] = m;
    __syncthreads();
    if (threadIdx.x == 0)
        bsum[blockIdx.x] = (wsum[0] + wsum[1]) + (wsum[2] + wsum[3]);
}

// Single wave: deterministic sum of block partials, scaled.
__global__ __launch_bounds__(64)
void final_kernel(const float* __restrict__ bsum, float* __restrict__ out,
                  int nb, float scale) {
    float s = 0.0f;
    for (int k = threadIdx.x; k < nb; k += 64)
        s += bsum[k];
    for (int off = 32; off > 0; off >>= 1)
        s += __shfl_down(s, off, 64);
    if (threadIdx.x == 0) out[0] = s * scale;
}

extern "C" void kernel_launch(void* const* d_in, const int* in_sizes, int n_in,
                              void* d_out, int out_size, void* d_ws, size_t ws_size,
                              hipStream_t stream) {
    const float* x = (const float*)d_in[0];  // [8, 8192, 3]
    const float* y = (const float*)d_in[1];  // [8, 8192, 3]
    float* out = (float*)d_out;

    const int BN = B_ * N_;

    float* partX = (float*)d_ws;
    float* partY = partX + (size_t)S_ * BN;
    float* bsum  = partY + (size_t)S_ * BN;

    // fused both-direction minpass: grid (8, 8, 32) = 2048 blocks
    minpass_kernel<<<dim3(N_ / (256 * Q_), B_, 2 * S_), 256, 0, stream>>>(x, y, partX, partY);

    const int nb = 2 * BN / 256;  // 512
    merge_kernel<<<nb, 256, 0, stream>>>(partX, partY, bsum, BN);
    final_kernel<<<1, 64, 0, stream>>>(bsum, out, nb, 1.0f / 65536.0f);
}

// Round 7
// 135.580 us; speedup vs baseline: 2.0280x; 1.0318x over previous
//
#include <hip/hip_runtime.h>
#include <math.h>

// Chamfer distance, B=8, N=M=8192, D=3, fp32.
// out = mean_m( min_n dist2 ) + mean_n( min_m dist2 )
//
// dist2 = |q|^2 + (|t|^2 - 2 q.t). Fused single minpass dispatch:
//  - grid.z 0..31: z<16 -> queries=x targets=y; z>=16 -> queries=y targets=x
//  - block computes its 512 target quads (-2t, |t|^2) into 8KB LDS
//  - R5: Q=8 queries/thread, 8-target inner unroll -> 8 ds_read_b128 per
//    224 VALU ops (1:28); a single wave self-hides LDS latency.
//  - no atomics (R2 lesson): per-(query,split) partial mins via plain
//    coalesced stores; merge + final reduce deterministically.

#define B_      8
#define N_      8192
#define Q_      8            // queries per thread
#define S_      16           // target splits per pass
#define CHUNK_  (N_ / S_)    // 512 targets per block

// ws layout: partX float[S_][B_*N_] (4MB), partY float[S_][B_*N_] (4MB), bsum[512]

__global__ __launch_bounds__(256)
void minpass_kernel(const float* __restrict__ x, const float* __restrict__ y,
                    float* __restrict__ partX, float* __restrict__ partY) {
    __shared__ float4 sq[CHUNK_];

    const int b    = blockIdx.y;
    const int z    = blockIdx.z;       // 0..31
    const int pass = z >> 4;           // 0: q=x,t=y   1: q=y,t=x
    const int s    = z & (S_ - 1);

    const float* qpts = pass ? y : x;
    const float* tpts = pass ? x : y;
    float*       part = pass ? partY : partX;

    // ---- stage: compute 512 target quads into LDS (2 per thread) ----
    {
        const float* p = tpts + ((long)b * N_ + s * CHUNK_) * 3 + 6 * threadIdx.x;
        float a0 = p[0], a1 = p[1], a2 = p[2];
        float a3 = p[3], a4 = p[4], a5 = p[5];
        sq[2 * threadIdx.x + 0] = make_float4(-2.0f * a0, -2.0f * a1, -2.0f * a2,
                                              fmaf(a0, a0, fmaf(a1, a1, a2 * a2)));
        sq[2 * threadIdx.x + 1] = make_float4(-2.0f * a3, -2.0f * a4, -2.0f * a5,
                                              fmaf(a3, a3, fmaf(a4, a4, a5 * a5)));
    }
    __syncthreads();

    // ---- queries: 8 consecutive points = 96B -> 6 coalesced float4 loads ----
    const int iq0 = (blockIdx.x * blockDim.x + threadIdx.x) * Q_;
    const float4* qp4 = (const float4*)(qpts + ((long)b * N_ + iq0) * 3);
    float qx[Q_], qy[Q_], qz[Q_];
    {
        const float4 f0 = qp4[0], f1 = qp4[1], f2 = qp4[2];
        const float4 f3 = qp4[3], f4 = qp4[4], f5 = qp4[5];
        qx[0]=f0.x; qy[0]=f0.y; qz[0]=f0.z;
        qx[1]=f0.w; qy[1]=f1.x; qz[1]=f1.y;
        qx[2]=f1.z; qy[2]=f1.w; qz[2]=f2.x;
        qx[3]=f2.y; qy[3]=f2.z; qz[3]=f2.w;
        qx[4]=f3.x; qy[4]=f3.y; qz[4]=f3.z;
        qx[5]=f3.w; qy[5]=f4.x; qz[5]=f4.y;
        qx[6]=f4.z; qy[6]=f4.w; qz[6]=f5.x;
        qx[7]=f5.y; qy[7]=f5.z; qz[7]=f5.w;
    }

    float m[Q_];
#pragma unroll
    for (int i = 0; i < Q_; ++i) m[i] = __builtin_inff();

    // ---- scan: 8 targets per iter, uniform-address LDS broadcast reads ----
    for (int j = 0; j < CHUNK_; j += 8) {
        float4 t[8];
#pragma unroll
        for (int k = 0; k < 8; ++k) t[k] = sq[j + k];
#pragma unroll
        for (int i = 0; i < Q_; ++i) {
            float s0 = fmaf(qx[i], t[0].x, fmaf(qy[i], t[0].y, fmaf(qz[i], t[0].z, t[0].w)));
            float s1 = fmaf(qx[i], t[1].x, fmaf(qy[i], t[1].y, fmaf(qz[i], t[1].z, t[1].w)));
            float s2 = fmaf(qx[i], t[2].x, fmaf(qy[i], t[2].y, fmaf(qz[i], t[2].z, t[2].w)));
            float s3 = fmaf(qx[i], t[3].x, fmaf(qy[i], t[3].y, fmaf(qz[i], t[3].z, t[3].w)));
            float s4 = fmaf(qx[i], t[4].x, fmaf(qy[i], t[4].y, fmaf(qz[i], t[4].z, t[4].w)));
            float s5 = fmaf(qx[i], t[5].x, fmaf(qy[i], t[5].y, fmaf(qz[i], t[5].z, t[5].w)));
            float s6 = fmaf(qx[i], t[6].x, fmaf(qy[i], t[6].y, fmaf(qz[i], t[6].z, t[6].w)));
            float s7 = fmaf(qx[i], t[7].x, fmaf(qy[i], t[7].y, fmaf(qz[i], t[7].z, t[7].w)));
            float u0 = fminf(fminf(s0, s1), s2);   // v_min3
            float u1 = fminf(fminf(s3, s4), s5);   // v_min3
            float u2 = fminf(fminf(s6, s7), u0);   // v_min3
            m[i]     = fminf(fminf(u1, u2), m[i]); // v_min3
        }
    }

    // ---- emit partial mins (two coalesced float4 stores) ----
    float r[Q_];
#pragma unroll
    for (int i = 0; i < Q_; ++i) {
        float xn = fmaf(qx[i], qx[i], fmaf(qy[i], qy[i], qz[i] * qz[i]));
        r[i] = fmaxf(m[i] + xn, 0.0f);   // clamp cancellation; dist2 >= 0
    }
    float* dst = part + (long)s * (B_ * N_) + (long)b * N_ + iq0;
    *(float4*)(dst + 0) = make_float4(r[0], r[1], r[2], r[3]);
    *(float4*)(dst + 4) = make_float4(r[4], r[5], r[6], r[7]);
}

// One thread per query slot: min over S_ partials, then deterministic block sum.
__global__ __launch_bounds__(256)
void merge_kernel(const float* __restrict__ partX, const float* __restrict__ partY,
                  float* __restrict__ bsum, int BN) {
    const int g = blockIdx.x * blockDim.x + threadIdx.x;
    const float* base = (g < BN) ? (partX + g) : (partY + (g - BN));

    float m = __builtin_inff();
#pragma unroll
    for (int s = 0; s < S_; ++s)
        m = fminf(m, base[(long)s * BN]);

    for (int off = 32; off > 0; off >>= 1)
        m += __shfl_down(m, off, 64);
    __shared__ float wsum[4];
    const int lane = threadIdx.x & 63;
    const int w    = threadIdx.x >> 6;
    if (lane == 0) wsum[w] = m;
    __syncthreads();
    if (threadIdx.x == 0)
        bsum[blockIdx.x] = (wsum[0] + wsum[1]) + (wsum[2] + wsum[3]);
}

// Single wave: deterministic sum of block partials, scaled.
__global__ __launch_bounds__(64)
void final_kernel(const float* __restrict__ bsum, float* __restrict__ out,
                  int nb, float scale) {
    float s = 0.0f;
    for (int k = threadIdx.x; k < nb; k += 64)
        s += bsum[k];
    for (int off = 32; off > 0; off >>= 1)
        s += __shfl_down(s, off, 64);
    if (threadIdx.x == 0) out[0] = s * scale;
}

extern "C" void kernel_launch(void* const* d_in, const int* in_sizes, int n_in,
                              void* d_out, int out_size, void* d_ws, size_t ws_size,
                              hipStream_t stream) {
    const float* x = (const float*)d_in[0];  // [8, 8192, 3]
    const float* y = (const float*)d_in[1];  // [8, 8192, 3]
    float* out = (float*)d_out;

    const int BN = B_ * N_;

    float* partX = (float*)d_ws;
    float* partY = partX + (size_t)S_ * BN;
    float* bsum  = partY + (size_t)S_ * BN;

    // fused both-direction minpass: grid (4, 8, 32) = 1024 blocks
    minpass_kernel<<<dim3(N_ / (256 * Q_), B_, 2 * S_), 256, 0, stream>>>(x, y, partX, partY);

    const int nb = 2 * BN / 256;  // 512
    merge_kernel<<<nb, 256, 0, stream>>>(partX, partY, bsum, BN);
    final_kernel<<<1, 64, 0, stream>>>(bsum, out, nb, 1.0f / 65536.0f);
}